// Round 4
// baseline (386.623 us; speedup 1.0000x reference)
//
#include <hip/hip_runtime.h>

// phi (B,2,H,W) f32 -> out (B,1,H,W) f32 ; splat ones with bilinear weights, wrap BC
constexpr int H = 2048;
constexpr int W = 2048;
constexpr int TH = 64, TW = 64;
constexpr int HALO = 8;                 // |phi|~N(0,1); max|z| over 33M draws ~5.7 << 8
constexpr int LH = TH + 2 * HALO;       // 80
constexpr int LW = TW + 2 * HALO;       // 80
constexpr int TILE_ELEMS = LH * LW;     // 6400
constexpr int TR = H / TH;              // 32
constexpr int TC = W / TW;              // 32

static_assert(LW * 4 == 320, "ds_add_f32 offsets below assume LW==80");

// Hardware LDS float atomic add: 4 corners from one base address + imm offsets.
// (atomicAdd on __shared__ float lowers to a CAS retry loop -> ~180cyc/op; this is ~5-10cyc.)
typedef __attribute__((address_space(3))) float lds_f32;
__device__ __forceinline__ void lds_fadd_corners(float* p, float w00, float w01,
                                                 float w10, float w11) {
    unsigned a = (unsigned)(uintptr_t)(lds_f32*)p;
    asm volatile("ds_add_f32 %0, %1\n\t"
                 "ds_add_f32 %0, %2 offset:4\n\t"
                 "ds_add_f32 %0, %3 offset:320\n\t"
                 "ds_add_f32 %0, %4 offset:324"
                 :: "v"(a), "v"(w00), "v"(w01), "v"(w10), "v"(w11)
                 : "memory");
}

// ---------------- Pass 1: splat into LDS tile, dump tile to workspace ----------------
__global__ __launch_bounds__(256)
void splat_pass1(const float* __restrict__ phi, float* __restrict__ wsTiles,
                 int* __restrict__ flag, float* __restrict__ out) {
    __shared__ float tile[TILE_ELEMS];   // 25.6 KB

    const int tilesPerImg = TR * TC;     // 1024
    int id = blockIdx.x;
    int b  = id / tilesPerImg;
    int t  = id - b * tilesPerImg;
    int ti = t / TC;
    int tj = t - ti * TC;
    int i0 = ti * TH;
    int j0 = tj * TW;

    for (int k = threadIdx.x; k < TILE_ELEMS; k += 256) tile[k] = 0.0f;
    __syncthreads();

    const float* phiB = phi + (size_t)b * 2 * H * W;
    float* outb = out + (size_t)b * H * W;

    #pragma unroll
    for (int qq = 0; qq < 4; ++qq) {
        int q  = threadIdx.x + qq * 256;
        int r  = q >> 4;
        int c4 = (q & 15) << 2;
        int i  = i0 + r;
        int j  = j0 + c4;
        const float4 p0 = *reinterpret_cast<const float4*>(phiB + (size_t)i * W + j);
        const float4 p1 = *reinterpret_cast<const float4*>(phiB + (size_t)H * W + (size_t)i * W + j);
        const float pxs[4] = {p0.x, p0.y, p0.z, p0.w};
        const float pys[4] = {p1.x, p1.y, p1.z, p1.w};

        #pragma unroll
        for (int e = 0; e < 4; ++e) {
            float x = (float)i + pxs[e];
            float y = (float)(j + e) + pys[e];
            float x0f = floorf(x), y0f = floorf(y);
            float wx1 = x - x0f, wy1 = y - y0f;
            float wx0 = 1.0f - wx1, wy0 = 1.0f - wy1;
            int ix0 = (int)x0f;
            int iy0 = (int)y0f;
            int lx = ix0 - (i0 - HALO);
            int ly = iy0 - (j0 - HALO);
            if ((unsigned)lx < (unsigned)(LH - 1) && (unsigned)ly < (unsigned)(LW - 1)) {
                lds_fadd_corners(tile + lx * LW + ly,
                                 wx0 * wy0, wx0 * wy1, wx1 * wy0, wx1 * wy1);
            } else {
                // statistically never for N(0,1); correctness for any input
                atomicExch(flag, 1);
                int gx0 = ix0 % H; if (gx0 < 0) gx0 += H;
                int gy0 = iy0 % W; if (gy0 < 0) gy0 += W;
                int gx1 = gx0 + 1; if (gx1 == H) gx1 = 0;
                int gy1 = gy0 + 1; if (gy1 == W) gy1 = 0;
                atomicAdd(outb + (size_t)gx0 * W + gy0, wx0 * wy0);
                atomicAdd(outb + (size_t)gx0 * W + gy1, wx0 * wy1);
                atomicAdd(outb + (size_t)gx1 * W + gy0, wx1 * wy0);
                atomicAdd(outb + (size_t)gx1 * W + gy1, wx1 * wy1);
            }
        }
    }
    __syncthreads();

    // dump whole tile (zeros included) to ws with vectorized plain stores
    float* wtile = wsTiles + (size_t)id * TILE_ELEMS;
    for (int k4 = threadIdx.x; k4 < TILE_ELEMS / 4; k4 += 256) {
        float4 v = *reinterpret_cast<const float4*>(tile + 4 * k4);
        *reinterpret_cast<float4*>(wtile + 4 * k4) = v;
    }
}

// ---------------- Pass 2: gather 1-4 ws cells per output pixel ----------------
__global__ __launch_bounds__(256)
void gather_pass2(const float* __restrict__ wsTiles, const int* __restrict__ flag,
                  float* __restrict__ out) {
    int tid = blockIdx.x * 256 + threadIdx.x;
    int q     = tid & 511;          // quad within row (W/4 = 512)
    int rowId = tid >> 9;           // b*H + r
    int b = rowId >> 11;            // H = 2048
    int r = rowId & 2047;
    int c4 = q << 2;

    int ti = r >> 6,  rl = r & 63;
    int tj = c4 >> 6, cl = c4 & 63;

    // row candidates (tile index, local row)
    int rt0 = ti, lr0 = rl + HALO;
    int nrow = 1, rt1 = 0, lr1 = 0;
    if (rl < HALO)            { rt1 = (ti + TR - 1) & (TR - 1); lr1 = rl + TH + HALO; nrow = 2; }
    else if (rl >= TH - HALO) { rt1 = (ti + 1) & (TR - 1);      lr1 = rl - (TH - HALO); nrow = 2; }

    // col candidates — uniform for all 4 pixels of the quad (cl % 4 == 0, cl+3 <= 63)
    int ct0 = tj, lc0 = cl + HALO;
    int ncol = 1, ct1 = 0, lc1 = 0;
    if (cl < HALO)            { ct1 = (tj + TC - 1) & (TC - 1); lc1 = cl + TW + HALO; ncol = 2; }
    else if (cl >= TW - HALO) { ct1 = (tj + 1) & (TC - 1);      lc1 = cl - (TW - HALO); ncol = 2; }

    const size_t tb = (size_t)b * (TR * TC);
    float4 s = make_float4(0.f, 0.f, 0.f, 0.f);

    auto acc = [&](int tr_, int tc_, int lr_, int lc_) {
        const float4 v = *reinterpret_cast<const float4*>(
            wsTiles + ((tb + (size_t)tr_ * TC + tc_) * TILE_ELEMS + (size_t)lr_ * LW + lc_));
        s.x += v.x; s.y += v.y; s.z += v.z; s.w += v.w;
    };

    acc(rt0, ct0, lr0, lc0);
    if (ncol == 2) acc(rt0, ct1, lr0, lc1);
    if (nrow == 2) {
        acc(rt1, ct0, lr1, lc0);
        if (ncol == 2) acc(rt1, ct1, lr1, lc1);
    }

    size_t oidx = ((size_t)b * H + r) * W + c4;
    if (*flag) {  // fallback atomics landed in out (never for this input); keep them
        const float4 ov = *reinterpret_cast<const float4*>(out + oidx);
        s.x += ov.x; s.y += ov.y; s.z += ov.z; s.w += ov.w;
    }
    *reinterpret_cast<float4*>(out + oidx) = s;
}

// ---------------- Fallback (ws too small): single-pass atomic-flush kernel ----------------
__global__ __launch_bounds__(256)
void splat_tile_atomic(const float* __restrict__ phi, float* __restrict__ out) {
    __shared__ float tile[TILE_ELEMS];
    const int tilesPerImg = TR * TC;
    int id = blockIdx.x;
    int b  = id / tilesPerImg;
    int t  = id - b * tilesPerImg;
    int ti = t / TC;
    int tj = t - ti * TC;
    int i0 = ti * TH;
    int j0 = tj * TW;

    for (int k = threadIdx.x; k < TILE_ELEMS; k += 256) tile[k] = 0.0f;
    __syncthreads();

    const float* phiB = phi + (size_t)b * 2 * H * W;
    float* outb = out + (size_t)b * H * W;

    #pragma unroll
    for (int qq = 0; qq < 4; ++qq) {
        int q  = threadIdx.x + qq * 256;
        int r  = q >> 4;
        int c4 = (q & 15) << 2;
        int i  = i0 + r;
        int j  = j0 + c4;
        const float4 p0 = *reinterpret_cast<const float4*>(phiB + (size_t)i * W + j);
        const float4 p1 = *reinterpret_cast<const float4*>(phiB + (size_t)H * W + (size_t)i * W + j);
        const float pxs[4] = {p0.x, p0.y, p0.z, p0.w};
        const float pys[4] = {p1.x, p1.y, p1.z, p1.w};
        #pragma unroll
        for (int e = 0; e < 4; ++e) {
            float x = (float)i + pxs[e];
            float y = (float)(j + e) + pys[e];
            float x0f = floorf(x), y0f = floorf(y);
            float wx1 = x - x0f, wy1 = y - y0f;
            float wx0 = 1.0f - wx1, wy0 = 1.0f - wy1;
            int ix0 = (int)x0f, iy0 = (int)y0f;
            int lx = ix0 - (i0 - HALO);
            int ly = iy0 - (j0 - HALO);
            if ((unsigned)lx < (unsigned)(LH - 1) && (unsigned)ly < (unsigned)(LW - 1)) {
                lds_fadd_corners(tile + lx * LW + ly,
                                 wx0 * wy0, wx0 * wy1, wx1 * wy0, wx1 * wy1);
            } else {
                int gx0 = ix0 % H; if (gx0 < 0) gx0 += H;
                int gy0 = iy0 % W; if (gy0 < 0) gy0 += W;
                int gx1 = gx0 + 1; if (gx1 == H) gx1 = 0;
                int gy1 = gy0 + 1; if (gy1 == W) gy1 = 0;
                atomicAdd(outb + (size_t)gx0 * W + gy0, wx0 * wy0);
                atomicAdd(outb + (size_t)gx0 * W + gy1, wx0 * wy1);
                atomicAdd(outb + (size_t)gx1 * W + gy0, wx1 * wy0);
                atomicAdd(outb + (size_t)gx1 * W + gy1, wx1 * wy1);
            }
        }
    }
    __syncthreads();

    for (int k = threadIdx.x; k < TILE_ELEMS; k += 256) {
        float v = tile[k];
        if (v != 0.0f) {
            int rr = k / LW;
            int cc = k - rr * LW;
            int gr = (i0 - HALO + rr) & (H - 1);
            int gc = (j0 - HALO + cc) & (W - 1);
            atomicAdd(outb + (size_t)gr * W + gc, v);
        }
    }
}

extern "C" void kernel_launch(void* const* d_in, const int* in_sizes, int n_in,
                              void* d_out, int out_size, void* d_ws, size_t ws_size,
                              hipStream_t stream) {
    const float* phi = (const float*)d_in[0];
    float* out = (float*)d_out;

    int B = out_size / (H * W);
    int nTiles = B * TR * TC;                                  // 4096
    size_t tilesBytes = (size_t)nTiles * TILE_ELEMS * sizeof(float);  // 104.86 MB
    size_t wsNeeded = tilesBytes + 16;

    hipMemsetAsync(out, 0, (size_t)out_size * sizeof(float), stream);

    if (ws_size >= wsNeeded) {
        float* wsTiles = (float*)d_ws;
        int* flag = (int*)((char*)d_ws + tilesBytes);
        hipMemsetAsync(flag, 0, sizeof(int), stream);
        splat_pass1<<<nTiles, 256, 0, stream>>>(phi, wsTiles, flag, out);
        int grid2 = out_size / 4 / 256;                        // 16384
        gather_pass2<<<grid2, 256, 0, stream>>>(wsTiles, flag, out);
    } else {
        splat_tile_atomic<<<nTiles, 256, 0, stream>>>(phi, out);
    }
}

// Round 5
// 186.339 us; speedup vs baseline: 2.0748x; 2.0748x over previous
//
#include <hip/hip_runtime.h>

// phi (B,2,H,W) f32 -> out (B,1,H,W) f32 ; splat ones with bilinear weights, wrap BC.
// Gather formulation: each wave owns (row r, 56 output cols); sweeps 7 source rows;
// per-lane register slots (static col offsets -3..3) accumulate; __shfl routes cols;
// one coalesced atomicAdd commits. Rare wide displacements (floor outside [-3,2])
// go through a scattered global-atomic fallback, committed exactly once.
constexpr int H = 2048, W = 2048;
constexpr int HW = H * W;
constexpr int OUTW = 56;                    // output cols per wave (64 lanes - 8 halo)
constexpr int NCH = (W + OUTW - 1) / OUTW;  // 37 col-chunks (last ragged)
constexpr int RPB = 4;                      // waves (rows) per 256-thread block

__global__ __launch_bounds__(256)
void splat_gather(const float* __restrict__ phi, float* __restrict__ out) {
    int wid  = threadIdx.x >> 6;
    int lane = threadIdx.x & 63;

    const int perB = NCH * (H / RPB);
    int bid = blockIdx.x;
    int b   = bid / perB;
    int rem = bid - b * perB;
    int c0i = rem / (H / RPB);
    int rg  = rem - c0i * (H / RPB);
    int r   = rg * RPB + wid;               // owned output row
    int c0  = c0i * OUTW;

    const float* phiB = phi + (size_t)b * 2 * HW;
    float* outb = out + (size_t)b * HW;

    int scu = c0 - 4 + lane;                // unwrapped source col of this lane
    int scw = scu & (W - 1);                // wrapped col for loads
    bool owned = (lane >= 4) && (lane < 4 + OUTW) && (scu < W);

    // prefetch the 7 candidate source rows (both displacement planes)
    float dxv[7], dyv[7];
    int srowv[7];
    #pragma unroll
    for (int t = 0; t < 7; ++t) {
        int srow = (r + t - 3) & (H - 1);
        srowv[t] = srow;
        dxv[t] = phiB[(size_t)srow * W + scw];
        dyv[t] = phiB[(size_t)HW + (size_t)srow * W + scw];
    }

    float slot[7];
    #pragma unroll
    for (int k = 0; k < 7; ++k) slot[k] = 0.0f;

    #pragma unroll
    for (int t = 0; t < 7; ++t) {
        const int di = t - 3;               // source row = r + di
        int srow = srowv[t];
        float x  = (float)srow + dxv[t];
        float x0 = floorf(x);
        float wx1 = x - x0, wx0 = 1.0f - wx1;
        int ifx = (int)x0 - srow;           // row floor-offset of this source
        float y  = (float)scw + dyv[t];
        float y0 = floorf(y);
        float wy1 = y - y0, wy0 = 1.0f - wy1;
        int ify = (int)y0 - scw;            // col floor-offset

        bool valid = ((unsigned)(ifx + 3) <= 5u) && ((unsigned)(ify + 3) <= 5u);

        // row-weight of this source toward owned row r:
        // hits r via floor corner iff ifx == -di (w = wx0), via +1 corner iff ifx == -di-1 (w = wx1)
        float rw = (ifx == -di) ? wx0 : ((ifx == -di - 1) ? wx1 : 0.0f);
        float A  = valid ? rw * wy0 : 0.0f;   // goes to col scu + ify
        float Bv = valid ? rw * wy1 : 0.0f;   // goes to col scu + ify + 1

        if (__any(A != 0.0f || Bv != 0.0f)) {
            #pragma unroll
            for (int k = 0; k < 7; ++k) {
                const int ko = k - 3;
                slot[k] += ((ify == ko) ? A : 0.0f) + ((ify == ko - 1) ? Bv : 0.0f);
            }
        }

        if (di == 0) {
            // wide-displacement fallback: committed exactly once, by the owner chunk of
            // this source col at its own row. Statistically ~0.5% of sources.
            if (__any((!valid) && owned)) {
                if ((!valid) && owned) {
                    int gx0 = ((int)x0) & (H - 1);
                    int gx1 = (gx0 + 1) & (H - 1);
                    int gy0 = ((int)y0) & (W - 1);
                    int gy1 = (gy0 + 1) & (W - 1);
                    atomicAdd(outb + (size_t)gx0 * W + gy0, wx0 * wy0);
                    atomicAdd(outb + (size_t)gx0 * W + gy1, wx0 * wy1);
                    atomicAdd(outb + (size_t)gx1 * W + gy0, wx1 * wy0);
                    atomicAdd(outb + (size_t)gx1 * W + gy1, wx1 * wy1);
                }
            }
        }
    }

    // route column slots: output col (c0+lane-4) pulls slot k from lane (lane-k)
    float v = 0.0f;
    #pragma unroll
    for (int k = 0; k < 7; ++k) {
        const int ko = k - 3;
        v += __shfl(slot[k], lane - ko);
    }
    // commit (atomicAdd so it commutes with the rare fallback atomics)
    if (owned) atomicAdd(outb + (size_t)r * W + scu, v);
}

extern "C" void kernel_launch(void* const* d_in, const int* in_sizes, int n_in,
                              void* d_out, int out_size, void* d_ws, size_t ws_size,
                              hipStream_t stream) {
    const float* phi = (const float*)d_in[0];
    float* out = (float*)d_out;

    hipMemsetAsync(out, 0, (size_t)out_size * sizeof(float), stream);

    int B = out_size / HW;
    int grid = B * NCH * (H / RPB);         // 4 * 37 * 512 = 75776 blocks
    splat_gather<<<grid, 256, 0, stream>>>(phi, out);
}

// Round 6
// 94.739 us; speedup vs baseline: 4.0809x; 1.9669x over previous
//
#include <hip/hip_runtime.h>

// phi (B,2,H,W) f32 -> out (B,1,H,W) f32 ; splat ones with bilinear weights, wrap BC.
// Gather formulation, tent weights, multi-row amortization:
//   each wave owns RB=4 output rows x 56 cols; scans RB+6 source rows once each;
//   col tent weights (7 static offsets) computed once per source, reused by all 4 rows;
//   per-lane register slots, __shfl column routing, one coalesced atomicAdd per pixel.
// Sources with |dx|>=3 or |dy|>=3 (P ~ 0.5% for N(0,1)) go through a scattered
// global-atomic fallback, committed exactly once by the wave owning that source row.
constexpr int H = 2048, W = 2048;
constexpr int HW = H * W;
constexpr int OUTW = 56;                    // output cols per wave (64 lanes - 8 halo)
constexpr int NCH = (W + OUTW - 1) / OUTW;  // 37 col-chunks (last ragged)
constexpr int RB  = 4;                      // owned rows per wave
constexpr int WPB = 4;                      // waves per block
constexpr int ROWSPB = RB * WPB;            // 16 rows per block
constexpr int NSRC = RB + 6;                // scanned source rows per wave

__global__ __launch_bounds__(256)
void splat_gather4(const float* __restrict__ phi, float* __restrict__ out) {
    int wid  = threadIdx.x >> 6;
    int lane = threadIdx.x & 63;

    const int rgPerImg = H / ROWSPB;        // 128
    int bid = blockIdx.x;
    int b   = bid / (NCH * rgPerImg);
    int rem = bid - b * (NCH * rgPerImg);
    int c0i = rem / rgPerImg;
    int rg  = rem - c0i * rgPerImg;
    int r0  = rg * ROWSPB + wid * RB;       // first owned row of this wave
    int c0  = c0i * OUTW;

    const float* phiB = phi + (size_t)b * 2 * HW;
    float* outb = out + (size_t)b * HW;

    int scu = c0 - 4 + lane;                // unwrapped source col of this lane
    int scw = scu & (W - 1);                // wrapped col for loads
    bool ownedCol = (lane >= 4) && (lane < 4 + OUTW) && (scu < W);

    // prefetch the NSRC candidate source rows (both displacement planes), coalesced
    float dxv[NSRC], dyv[NSRC];
    #pragma unroll
    for (int t = 0; t < NSRC; ++t) {
        int srow = (r0 + t - 3) & (H - 1);
        dxv[t] = phiB[(size_t)srow * W + scw];
        dyv[t] = phiB[(size_t)HW + (size_t)srow * W + scw];
    }

    float slot[RB][7];
    #pragma unroll
    for (int m = 0; m < RB; ++m)
        #pragma unroll
        for (int k = 0; k < 7; ++k) slot[m][k] = 0.0f;

    #pragma unroll
    for (int t = 0; t < NSRC; ++t) {
        float dx = dxv[t], dy = dyv[t];
        bool valid = (__builtin_fabsf(dx) < 3.0f) && (__builtin_fabsf(dy) < 3.0f);
        float dyM = valid ? dy : 16384.0f;   // invalid -> all col tents 0 -> fallback only

        // col tent weights toward offsets ko = k-3 (same for all owned rows)
        float ct[7];
        #pragma unroll
        for (int k = 0; k < 7; ++k) {
            float d = dyM - (float)(k - 3);
            ct[k] = __builtin_fmaxf(1.0f - __builtin_fabsf(d), 0.0f);
        }

        // row tents toward owned rows + rank-1 accumulate
        #pragma unroll
        for (int m = 0; m < RB; ++m) {
            float dist = dx + (float)(t - 3 - m);   // x - (r0+m), unwrapped
            float rw = __builtin_fmaxf(1.0f - __builtin_fabsf(dist), 0.0f);
            #pragma unroll
            for (int k = 0; k < 7; ++k)
                slot[m][k] = __builtin_fmaf(rw, ct[k], slot[m][k]);
        }

        // wide-displacement fallback: this wave owns source row r0+(t-3) for t in [3,3+RB)
        if (t >= 3 && t < 3 + RB) {
            if (__any((!valid) && ownedCol)) {
                if ((!valid) && ownedCol) {
                    int srow = (r0 + t - 3) & (H - 1);
                    float x = (float)srow + dx;
                    float y = (float)scw + dy;
                    float x0 = floorf(x), y0 = floorf(y);
                    float wx1 = x - x0, wx0 = 1.0f - wx1;
                    float wy1 = y - y0, wy0 = 1.0f - wy1;
                    int gx0 = ((int)x0) & (H - 1);
                    int gx1 = (gx0 + 1) & (H - 1);
                    int gy0 = ((int)y0) & (W - 1);
                    int gy1 = (gy0 + 1) & (W - 1);
                    atomicAdd(outb + (size_t)gx0 * W + gy0, wx0 * wy0);
                    atomicAdd(outb + (size_t)gx0 * W + gy1, wx0 * wy1);
                    atomicAdd(outb + (size_t)gx1 * W + gy0, wx1 * wy0);
                    atomicAdd(outb + (size_t)gx1 * W + gy1, wx1 * wy1);
                }
            }
        }
    }

    // route column slots and commit: output col (c0+lane-4) pulls slot k from lane (lane-ko)
    #pragma unroll
    for (int m = 0; m < RB; ++m) {
        float v = 0.0f;
        #pragma unroll
        for (int k = 0; k < 7; ++k)
            v += __shfl(slot[m][k], lane - (k - 3));
        if (ownedCol)
            atomicAdd(outb + (size_t)(r0 + m) * W + scu, v);
    }
}

extern "C" void kernel_launch(void* const* d_in, const int* in_sizes, int n_in,
                              void* d_out, int out_size, void* d_ws, size_t ws_size,
                              hipStream_t stream) {
    const float* phi = (const float*)d_in[0];
    float* out = (float*)d_out;

    hipMemsetAsync(out, 0, (size_t)out_size * sizeof(float), stream);

    int B = out_size / HW;
    int grid = B * NCH * (H / ROWSPB);      // 4 * 37 * 128 = 18944 blocks
    splat_gather4<<<grid, 256, 0, stream>>>(phi, out);
}